// Round 8
// baseline (295.947 us; speedup 1.0000x reference)
//
#include <hip/hip_runtime.h>
#include <math.h>

#define NROWS 64
#define DCOLS 512
#define BDIM  1024
#define RPW   4     // rows per wave: 64 rows / 16 waves
#define BPB   8     // batch elements per block (prefetch pipeline depth)

typedef float f32x4 __attribute__((ext_vector_type(4)));

__device__ __forceinline__ void wave_reduce_sum2(float& a, float& b) {
#pragma unroll
    for (int off = 32; off > 0; off >>= 1) {
        a += __shfl_xor(a, off, 64);
        b += __shfl_xor(b, off, 64);
    }
}
__device__ __forceinline__ float wave_reduce_sum(float v) {
#pragma unroll
    for (int off = 32; off > 0; off >>= 1)
        v += __shfl_xor(v, off, 64);
    return v;
}
__device__ __forceinline__ float wave_reduce_max(float v) {
#pragma unroll
    for (int off = 32; off > 0; off >>= 1)
        v = fmaxf(v, __shfl_xor(v, off, 64));
    return v;
}

__device__ __forceinline__ float hsum8(f32x4 a, f32x4 b) {
    return ((a.x + a.y) + (a.z + a.w)) + ((b.x + b.y) + (b.z + b.w));
}
__device__ __forceinline__ float hsumsq8(f32x4 a, f32x4 b) {
    return (a.x*a.x + a.y*a.y + a.z*a.z + a.w*a.w)
         + (b.x*b.x + b.y*b.y + b.z*b.z + b.w*b.w);
}

// tanh(x) = 1 - 2/(exp(2x)+1); correct both signs, saturates at +/-1.
__device__ __forceinline__ float fast_tanh(float x) {
    float e = __expf(2.0f * x);
    return 1.0f - 2.0f / (e + 1.0f);
}

__global__ __launch_bounds__(BDIM, 4) void fused_ln_attn_kernel(
    const float* __restrict__ emb,
    const float* __restrict__ gamma,
    const float* __restrict__ beta,
    const float* __restrict__ Wv,
    const float* __restrict__ bv,
    float* __restrict__ out,
    int B)
{
    __shared__ float s_q[DCOLS];
    __shared__ float s_sc[NROWS];   // scores; s_sc[0] = -inf sentinel

    const int tid  = threadIdx.x;
    const int wave = tid >> 6;
    const int lane = tid & 63;
    const int c0   = lane << 2;
    const int c1   = 256 + c0;
    const int r0   = wave * RPW;

    // loop-invariant params (live whole kernel)
    const f32x4 g0 = *(const f32x4*)(gamma + c0);
    const f32x4 g1 = *(const f32x4*)(gamma + c1);
    const f32x4 b0 = *(const f32x4*)(beta + c0);
    const f32x4 b1 = *(const f32x4*)(beta + c1);
    const f32x4 w0 = *(const f32x4*)(Wv + c0);
    const f32x4 w1 = *(const f32x4*)(Wv + c1);
    const float bias = bv[0];

    const int bstart = blockIdx.x * BPB;

    // preload first batch's x into the pipeline registers
    f32x4 cx0[RPW], cx1[RPW];
    {
        const float* eb = emb + (size_t)bstart * (NROWS * DCOLS);
#pragma unroll
        for (int i = 0; i < RPW; ++i) {
            const float* rp = eb + (r0 + i) * DCOLS;
            cx0[i] = *(const f32x4*)(rp + c0);
            cx1[i] = *(const f32x4*)(rp + c1);
        }
    }

#pragma unroll 1
    for (int t = 0; t < BPB; ++t) {
        const int bb = bstart + t;
        if (bb >= B) break;
        float* ob = out + (size_t)bb * (NROWS * DCOLS);

        // ---- Pass 1: LN from pipeline regs -> e regs ----
        f32x4 e0[RPW], e1[RPW];
#pragma unroll
        for (int i = 0; i < RPW; ++i) {
            float s = hsum8(cx0[i], cx1[i]), ss = hsumsq8(cx0[i], cx1[i]);
            wave_reduce_sum2(s, ss);
            const float mu  = s * (1.0f / (float)DCOLS);
            const float var = ss * (1.0f / (float)DCOLS) - mu * mu;
            const float rs  = rsqrtf(var + 1e-5f);
            e0[i] = (cx0[i] - mu) * rs * g0 + b0;
            e1[i] = (cx1[i] - mu) * rs * g1 + b1;
            if (wave == 0 && i == 0) {
                *(f32x4*)(s_q + c0) = e0[0];
                *(f32x4*)(s_q + c1) = e1[0];
                __builtin_nontemporal_store(e0[0], (f32x4*)(ob + c0));
                __builtin_nontemporal_store(e1[0], (f32x4*)(ob + c1));
            }
        }

        // ---- Prefetch next batch's x (in flight across pass 2/3) ----
        if (t + 1 < BPB && bb + 1 < B) {
            const float* nb = emb + (size_t)(bb + 1) * (NROWS * DCOLS);
#pragma unroll
            for (int i = 0; i < RPW; ++i) {
                const float* rp = nb + (r0 + i) * DCOLS;
                cx0[i] = *(const f32x4*)(rp + c0);
                cx1[i] = *(const f32x4*)(rp + c1);
            }
        }

        __syncthreads();   // barrier 1: q visible

        const f32x4 q0 = *(const f32x4*)(s_q + c0);
        const f32x4 q1 = *(const f32x4*)(s_q + c1);

        // ---- Pass 2: scores ----
        float sc[RPW];
#pragma unroll
        for (int i = 0; i < RPW; ++i) {
            const int r = r0 + i;
            float p = 0.0f;
            if (r > 0) {
                p  = fast_tanh(q0.x * e0[i].x) * w0.x;
                p += fast_tanh(q0.y * e0[i].y) * w0.y;
                p += fast_tanh(q0.z * e0[i].z) * w0.z;
                p += fast_tanh(q0.w * e0[i].w) * w0.w;
                p += fast_tanh(q1.x * e1[i].x) * w1.x;
                p += fast_tanh(q1.y * e1[i].y) * w1.y;
                p += fast_tanh(q1.z * e1[i].z) * w1.z;
                p += fast_tanh(q1.w * e1[i].w) * w1.w;
            }
            const float tot = wave_reduce_sum(p) + bias;
            sc[i] = tot;
            if (lane == 0) s_sc[r] = (r > 0) ? tot : -1e30f;
        }
        __syncthreads();   // barrier 2: scores visible

        // ---- Softmax stats: every wave reduces the 64-entry score vector ----
        const float v   = s_sc[lane];
        const float mx  = wave_reduce_max(v);
        const float den = wave_reduce_sum(__expf(v - mx));
        const float inv = 1.0f / den;

        // ---- Pass 3: scale + store ----
#pragma unroll
        for (int i = 0; i < RPW; ++i) {
            const int r = r0 + i;
            if (r == 0) continue;
            const float a = __expf(sc[i] - mx) * inv;
            __builtin_nontemporal_store(e0[i] * a, (f32x4*)(ob + r * DCOLS + c0));
            __builtin_nontemporal_store(e1[i] * a, (f32x4*)(ob + r * DCOLS + c1));
        }
    }
}

extern "C" void kernel_launch(void* const* d_in, const int* in_sizes, int n_in,
                              void* d_out, int out_size, void* d_ws, size_t ws_size,
                              hipStream_t stream) {
    const float* emb   = (const float*)d_in[0];
    const float* gamma = (const float*)d_in[1];
    const float* beta  = (const float*)d_in[2];
    const float* Wv    = (const float*)d_in[3];
    const float* bv    = (const float*)d_in[4];
    float* out = (float*)d_out;

    const int B = in_sizes[0] / (NROWS * DCOLS);
    const int grid = (B + BPB - 1) / BPB;
    fused_ln_attn_kernel<<<grid, BDIM, 0, stream>>>(emb, gamma, beta, Wv, bv, out, B);
}

// Round 9
// 290.703 us; speedup vs baseline: 1.0180x; 1.0180x over previous
//
#include <hip/hip_runtime.h>
#include <math.h>

#define NROWS 64
#define DCOLS 512
#define BDIM  1024
#define RPW   4     // rows per wave: 64 rows / 16 waves
#define BPB   16    // batch elements per block (grid = 4096/16 = 256 = 1 block/CU)

typedef float f32x4 __attribute__((ext_vector_type(4)));

__device__ __forceinline__ void wave_reduce_sum2(float& a, float& b) {
#pragma unroll
    for (int off = 32; off > 0; off >>= 1) {
        a += __shfl_xor(a, off, 64);
        b += __shfl_xor(b, off, 64);
    }
}
__device__ __forceinline__ float wave_reduce_sum(float v) {
#pragma unroll
    for (int off = 32; off > 0; off >>= 1)
        v += __shfl_xor(v, off, 64);
    return v;
}
__device__ __forceinline__ float wave_reduce_max(float v) {
#pragma unroll
    for (int off = 32; off > 0; off >>= 1)
        v = fmaxf(v, __shfl_xor(v, off, 64));
    return v;
}

__device__ __forceinline__ float hsum8(f32x4 a, f32x4 b) {
    return ((a.x + a.y) + (a.z + a.w)) + ((b.x + b.y) + (b.z + b.w));
}
__device__ __forceinline__ float hsumsq8(f32x4 a, f32x4 b) {
    return (a.x*a.x + a.y*a.y + a.z*a.z + a.w*a.w)
         + (b.x*b.x + b.y*b.y + b.z*b.z + b.w*b.w);
}

// tanh(x) = 1 - 2/(exp(2x)+1); correct both signs, saturates at +/-1.
__device__ __forceinline__ float fast_tanh(float x) {
    float e = __expf(2.0f * x);
    return 1.0f - 2.0f / (e + 1.0f);
}

__global__ __launch_bounds__(BDIM)
__attribute__((amdgpu_waves_per_eu(4, 4)))   // pin 4 waves/EU: full 128-VGPR tier, no spill-for-occupancy
void fused_ln_attn_kernel(
    const float* __restrict__ emb,
    const float* __restrict__ gamma,
    const float* __restrict__ beta,
    const float* __restrict__ Wv,
    const float* __restrict__ bv,
    float* __restrict__ out,
    int B)
{
    __shared__ float s_q[DCOLS];
    __shared__ float s_sc[NROWS];   // scores; s_sc[0] = -inf sentinel

    const int tid  = threadIdx.x;
    const int wave = tid >> 6;
    const int lane = tid & 63;
    const int c0   = lane << 2;
    const int c1   = 256 + c0;
    const int r0   = wave * RPW;

    // loop-invariant params (live whole kernel)
    const f32x4 g0 = *(const f32x4*)(gamma + c0);
    const f32x4 g1 = *(const f32x4*)(gamma + c1);
    const f32x4 b0 = *(const f32x4*)(beta + c0);
    const f32x4 b1 = *(const f32x4*)(beta + c1);
    const f32x4 w0 = *(const f32x4*)(Wv + c0);
    const f32x4 w1 = *(const f32x4*)(Wv + c1);
    const float bias = bv[0];

    const int bstart = blockIdx.x * BPB;

    // preload first batch's x into the pipeline registers
    f32x4 cx0[RPW], cx1[RPW];
    {
        const float* eb = emb + (size_t)bstart * (NROWS * DCOLS);
#pragma unroll
        for (int i = 0; i < RPW; ++i) {
            const float* rp = eb + (r0 + i) * DCOLS;
            cx0[i] = *(const f32x4*)(rp + c0);
            cx1[i] = *(const f32x4*)(rp + c1);
        }
    }

#pragma unroll 1
    for (int t = 0; t < BPB; ++t) {
        const int bb = bstart + t;
        if (bb >= B) break;
        float* ob = out + (size_t)bb * (NROWS * DCOLS);

        // ---- Pass 1: LN from pipeline regs -> e regs ----
        f32x4 e0[RPW], e1[RPW];
#pragma unroll
        for (int i = 0; i < RPW; ++i) {
            float s = hsum8(cx0[i], cx1[i]), ss = hsumsq8(cx0[i], cx1[i]);
            wave_reduce_sum2(s, ss);
            const float mu  = s * (1.0f / (float)DCOLS);
            const float var = ss * (1.0f / (float)DCOLS) - mu * mu;
            const float rs  = rsqrtf(var + 1e-5f);
            e0[i] = (cx0[i] - mu) * rs * g0 + b0;
            e1[i] = (cx1[i] - mu) * rs * g1 + b1;
            if (wave == 0 && i == 0) {
                *(f32x4*)(s_q + c0) = e0[0];
                *(f32x4*)(s_q + c1) = e1[0];
                __builtin_nontemporal_store(e0[0], (f32x4*)(ob + c0));
                __builtin_nontemporal_store(e1[0], (f32x4*)(ob + c1));
            }
        }

        // ---- Prefetch next batch's x: issue NOW, consume next iteration ----
        if (t + 1 < BPB && bb + 1 < B) {
            const float* nb = emb + (size_t)(bb + 1) * (NROWS * DCOLS);
#pragma unroll
            for (int i = 0; i < RPW; ++i) {
                const float* rp = nb + (r0 + i) * DCOLS;
                cx0[i] = *(const f32x4*)(rp + c0);
                cx1[i] = *(const f32x4*)(rp + c1);
            }
        }
        __builtin_amdgcn_sched_barrier(0);   // don't let the prefetch loads sink

        __syncthreads();   // barrier 1: q visible

        const f32x4 q0 = *(const f32x4*)(s_q + c0);
        const f32x4 q1 = *(const f32x4*)(s_q + c1);

        // ---- Pass 2: scores ----
        float sc[RPW];
#pragma unroll
        for (int i = 0; i < RPW; ++i) {
            const int r = r0 + i;
            float p = 0.0f;
            if (r > 0) {
                p  = fast_tanh(q0.x * e0[i].x) * w0.x;
                p += fast_tanh(q0.y * e0[i].y) * w0.y;
                p += fast_tanh(q0.z * e0[i].z) * w0.z;
                p += fast_tanh(q0.w * e0[i].w) * w0.w;
                p += fast_tanh(q1.x * e1[i].x) * w1.x;
                p += fast_tanh(q1.y * e1[i].y) * w1.y;
                p += fast_tanh(q1.z * e1[i].z) * w1.z;
                p += fast_tanh(q1.w * e1[i].w) * w1.w;
            }
            const float tot = wave_reduce_sum(p) + bias;
            sc[i] = tot;
            if (lane == 0) s_sc[r] = (r > 0) ? tot : -1e30f;
        }
        __syncthreads();   // barrier 2: scores visible

        // ---- Softmax stats: every wave reduces the 64-entry score vector ----
        const float v   = s_sc[lane];
        const float mx  = wave_reduce_max(v);
        const float den = wave_reduce_sum(__expf(v - mx));
        const float inv = 1.0f / den;

        // ---- Pass 3: scale + store ----
#pragma unroll
        for (int i = 0; i < RPW; ++i) {
            const int r = r0 + i;
            if (r == 0) continue;
            const float a = __expf(sc[i] - mx) * inv;
            __builtin_nontemporal_store(e0[i] * a, (f32x4*)(ob + r * DCOLS + c0));
            __builtin_nontemporal_store(e1[i] * a, (f32x4*)(ob + r * DCOLS + c1));
        }
    }
}

extern "C" void kernel_launch(void* const* d_in, const int* in_sizes, int n_in,
                              void* d_out, int out_size, void* d_ws, size_t ws_size,
                              hipStream_t stream) {
    const float* emb   = (const float*)d_in[0];
    const float* gamma = (const float*)d_in[1];
    const float* beta  = (const float*)d_in[2];
    const float* Wv    = (const float*)d_in[3];
    const float* bv    = (const float*)d_in[4];
    float* out = (float*)d_out;

    const int B = in_sizes[0] / (NROWS * DCOLS);
    const int grid = (B + BPB - 1) / BPB;
    fused_ln_attn_kernel<<<grid, BDIM, 0, stream>>>(emb, gamma, beta, Wv, bv, out, B);
}

// Round 10
// 231.426 us; speedup vs baseline: 1.2788x; 1.2561x over previous
//
#include <hip/hip_runtime.h>
#include <math.h>

#define NROWS 64
#define DCOLS 512
#define BDIM  512
#define RPW   8     // rows per wave: 64 rows / 8 waves

typedef float f32x4 __attribute__((ext_vector_type(4)));

__device__ __forceinline__ void wave_reduce_sum2(float& a, float& b) {
#pragma unroll
    for (int off = 32; off > 0; off >>= 1) {
        a += __shfl_xor(a, off, 64);
        b += __shfl_xor(b, off, 64);
    }
}
__device__ __forceinline__ float wave_reduce_sum(float v) {
#pragma unroll
    for (int off = 32; off > 0; off >>= 1)
        v += __shfl_xor(v, off, 64);
    return v;
}
__device__ __forceinline__ float wave_reduce_max(float v) {
#pragma unroll
    for (int off = 32; off > 0; off >>= 1)
        v = fmaxf(v, __shfl_xor(v, off, 64));
    return v;
}

__device__ __forceinline__ float hsum8(f32x4 a, f32x4 b) {
    return ((a.x + a.y) + (a.z + a.w)) + ((b.x + b.y) + (b.z + b.w));
}
__device__ __forceinline__ float hsumsq8(f32x4 a, f32x4 b) {
    return (a.x*a.x + a.y*a.y + a.z*a.z + a.w*a.w)
         + (b.x*b.x + b.y*b.y + b.z*b.z + b.w*b.w);
}

// tanh(x) = 1 - 2/(exp(2x)+1); correct both signs, saturates at +/-1.
__device__ __forceinline__ float fast_tanh(float x) {
    float e = __expf(2.0f * x);
    return 1.0f - 2.0f / (e + 1.0f);
}

__global__ __launch_bounds__(BDIM, 4) void fused_ln_attn_kernel(
    const float* __restrict__ emb,
    const float* __restrict__ gamma,
    const float* __restrict__ beta,
    const float* __restrict__ Wv,
    const float* __restrict__ bv,
    float* __restrict__ out)
{
    __shared__ float s_q[DCOLS];
    __shared__ float s_sc[NROWS];       // scores; s_sc[0] = -inf sentinel
    // Occupancy governor: caps blocks/CU at 2, which drops the register
    // allocator's occupancy target to 4 waves/EU -> 128-VGPR budget -> no
    // spill-for-occupancy (the R4/R8/R9 failure). Referenced via a
    // data-dependent never-taken branch so it can't be eliminated.
    __shared__ float s_pad[16384];      // 64 KiB

    const int tid  = threadIdx.x;
    const int wave = tid >> 6;
    const int lane = tid & 63;
    const int c0   = lane << 2;
    const int c1   = 256 + c0;
    const int r0   = wave * RPW;

    const size_t base = (size_t)blockIdx.x * (size_t)(NROWS * DCOLS);
    const float* eb = emb + base;
    float*       ob = out + base;

    const float bias = bv[0];
    if (bias == 12345.6789f) s_pad[tid] = bias;   // never true; keeps s_pad live

    f32x4 e0[RPW], e1[RPW];   // full normalized rows in registers (64 VGPR)

    // ---- Pass 1: LayerNorm each owned row (gamma/beta scoped here) ----
    {
        const f32x4 g0 = *(const f32x4*)(gamma + c0);
        const f32x4 g1 = *(const f32x4*)(gamma + c1);
        const f32x4 b0 = *(const f32x4*)(beta + c0);
        const f32x4 b1 = *(const f32x4*)(beta + c1);

#pragma unroll
        for (int i = 0; i < RPW; ++i) {
            const int r = r0 + i;
            const float* rp = eb + r * DCOLS;
            const f32x4 x0 = *(const f32x4*)(rp + c0);
            const f32x4 x1 = *(const f32x4*)(rp + c1);

            float s = hsum8(x0, x1), ss = hsumsq8(x0, x1);
            wave_reduce_sum2(s, ss);

            const float mu  = s * (1.0f / (float)DCOLS);
            const float var = ss * (1.0f / (float)DCOLS) - mu * mu;
            const float rs  = rsqrtf(var + 1e-5f);

            e0[i] = (x0 - mu) * rs * g0 + b0;
            e1[i] = (x1 - mu) * rs * g1 + b1;

            if (wave == 0 && i == 0) {
                // query row: publish to all waves + write straight to output
                *(f32x4*)(s_q + c0) = e0[0];
                *(f32x4*)(s_q + c1) = e1[0];
                __builtin_nontemporal_store(e0[0], (f32x4*)(ob + c0));
                __builtin_nontemporal_store(e1[0], (f32x4*)(ob + c1));
            }
        }
    }
    __syncthreads();   // barrier 1: q visible

    const f32x4 q0 = *(const f32x4*)(s_q + c0);
    const f32x4 q1 = *(const f32x4*)(s_q + c1);
    const f32x4 w0 = *(const f32x4*)(Wv + c0);
    const f32x4 w1 = *(const f32x4*)(Wv + c1);

    // ---- Pass 2: scores_r = sum_d tanh(q_d * e_rd) * Wv_d + bv ----
    float sc[RPW];
#pragma unroll
    for (int i = 0; i < RPW; ++i) {
        const int r = r0 + i;
        float p = 0.0f;
        if (r > 0) {
            p  = fast_tanh(q0.x * e0[i].x) * w0.x;
            p += fast_tanh(q0.y * e0[i].y) * w0.y;
            p += fast_tanh(q0.z * e0[i].z) * w0.z;
            p += fast_tanh(q0.w * e0[i].w) * w0.w;
            p += fast_tanh(q1.x * e1[i].x) * w1.x;
            p += fast_tanh(q1.y * e1[i].y) * w1.y;
            p += fast_tanh(q1.z * e1[i].z) * w1.z;
            p += fast_tanh(q1.w * e1[i].w) * w1.w;
        }
        const float tot = wave_reduce_sum(p) + bias;
        sc[i] = tot;
        if (lane == 0) s_sc[r] = (r > 0) ? tot : -1e30f;
    }
    __syncthreads();   // barrier 2: all scores visible

    // ---- Softmax stats: every wave reduces the 64-entry score vector ----
    const float v   = s_sc[lane];
    const float mx  = wave_reduce_max(v);
    const float den = wave_reduce_sum(__expf(v - mx));   // row-0 sentinel -> 0
    const float inv = 1.0f / den;

    // ---- Pass 3: scale + store ----
#pragma unroll
    for (int i = 0; i < RPW; ++i) {
        const int r = r0 + i;
        if (r == 0) continue;   // row 0 already written (it's q)
        const float a = __expf(sc[i] - mx) * inv;
        __builtin_nontemporal_store(e0[i] * a, (f32x4*)(ob + r * DCOLS + c0));
        __builtin_nontemporal_store(e1[i] * a, (f32x4*)(ob + r * DCOLS + c1));
    }
}

extern "C" void kernel_launch(void* const* d_in, const int* in_sizes, int n_in,
                              void* d_out, int out_size, void* d_ws, size_t ws_size,
                              hipStream_t stream) {
    const float* emb   = (const float*)d_in[0];
    const float* gamma = (const float*)d_in[1];
    const float* beta  = (const float*)d_in[2];
    const float* Wv    = (const float*)d_in[3];
    const float* bv    = (const float*)d_in[4];
    float* out = (float*)d_out;

    const int B = in_sizes[0] / (NROWS * DCOLS);
    fused_ln_attn_kernel<<<B, BDIM, 0, stream>>>(emb, gamma, beta, Wv, bv, out);
}

// Round 11
// 221.898 us; speedup vs baseline: 1.3337x; 1.0429x over previous
//
#include <hip/hip_runtime.h>
#include <math.h>

#define NROWS 64
#define DCOLS 512
#define HCOL  256
#define BDIM  512
#define RPW   8     // rows per wave: 64 rows / 8 waves
#define BPB   8     // batches per block: grid = 4096/8 = 512 = 2 blocks/CU exactly

typedef float f32x4 __attribute__((ext_vector_type(4)));

__device__ __forceinline__ void wave_reduce_sum2(float& a, float& b) {
#pragma unroll
    for (int off = 32; off > 0; off >>= 1) {
        a += __shfl_xor(a, off, 64);
        b += __shfl_xor(b, off, 64);
    }
}
__device__ __forceinline__ float wave_reduce_sum(float v) {
#pragma unroll
    for (int off = 32; off > 0; off >>= 1)
        v += __shfl_xor(v, off, 64);
    return v;
}

__device__ __forceinline__ float hsum8(f32x4 a, f32x4 b) {
    return ((a.x + a.y) + (a.z + a.w)) + ((b.x + b.y) + (b.z + b.w));
}
__device__ __forceinline__ float hsumsq8(f32x4 a, f32x4 b) {
    return (a.x*a.x + a.y*a.y + a.z*a.z + a.w*a.w)
         + (b.x*b.x + b.y*b.y + b.z*b.z + b.w*b.w);
}

// tanh(x) = 1 - 2/(exp(2x)+1); correct both signs, saturates at +/-1.
__device__ __forceinline__ float fast_tanh(float x) {
    float e = __expf(2.0f * x);
    return 1.0f - 2.0f / (e + 1.0f);
}

// LDS-ordering barrier that does NOT drain vmcnt: global prefetch loads and
// nontemporal stores stay in flight across it (unlike __syncthreads, which
// the compiler precedes with s_waitcnt vmcnt(0)).
__device__ __forceinline__ void lds_barrier() {
    asm volatile("s_waitcnt lgkmcnt(0)" ::: "memory");
    __builtin_amdgcn_s_barrier();
}

__global__ __launch_bounds__(BDIM, 4) void fused_ln_attn_kernel(
    const float* __restrict__ emb,
    const float* __restrict__ gamma,
    const float* __restrict__ beta,
    const float* __restrict__ Wv,
    const float* __restrict__ bv,
    float* __restrict__ out,
    int B)
{
    // 73.8 KiB total -> 2 blocks/CU (LDS cap). This also pins the register
    // allocator's occupancy target at 4 waves/EU -> 128-VGPR budget (the
    // R10-verified mechanism that prevents spill-for-occupancy).
    __shared__ __align__(16) float s_e1[NROWS * HCOL];  // 64 KiB: c1-half of e
    __shared__ __align__(16) float s_q[DCOLS];
    __shared__ __align__(16) float s_g[DCOLS];
    __shared__ __align__(16) float s_b[DCOLS];
    __shared__ __align__(16) float s_w[DCOLS];
    __shared__ float s_den[RPW];

    const int tid  = threadIdx.x;
    const int wave = tid >> 6;
    const int lane = tid & 63;
    const int c0   = lane << 2;
    const int c1   = HCOL + c0;
    const int r0   = wave * RPW;

    // stage params in LDS (don't burn persistent VGPRs on them)
    s_g[tid] = gamma[tid];
    s_b[tid] = beta[tid];
    s_w[tid] = Wv[tid];
    const float bias = bv[0];

    const int bstart = blockIdx.x * BPB;

    // prologue prefetch: first batch's c0-half
    f32x4 cx0[RPW];
    {
        const float* eb = emb + (size_t)bstart * (NROWS * DCOLS);
#pragma unroll
        for (int i = 0; i < RPW; ++i)
            cx0[i] = *(const f32x4*)(eb + (r0 + i) * DCOLS + c0);
    }
    lds_barrier();   // params visible

#pragma unroll 1
    for (int t = 0; t < BPB; ++t) {
        const int bb = bstart + t;
        if (bb >= B) break;
        const float* eb = emb + (size_t)bb * (NROWS * DCOLS);
        float*       ob = out + (size_t)bb * (NROWS * DCOLS);

        // ---- Pass 1: LayerNorm; e0 half -> regs, e1 half -> LDS ----
        f32x4 e0[RPW];
        {
            const f32x4 g0 = *(const f32x4*)(s_g + c0);
            const f32x4 g1 = *(const f32x4*)(s_g + c1);
            const f32x4 b0 = *(const f32x4*)(s_b + c0);
            const f32x4 b1 = *(const f32x4*)(s_b + c1);
#pragma unroll
            for (int i = 0; i < RPW; ++i) {
                const int r = r0 + i;
                const f32x4 x0 = cx0[i];
                const f32x4 x1 = *(const f32x4*)(eb + r * DCOLS + c1);

                float s = hsum8(x0, x1), ss = hsumsq8(x0, x1);
                wave_reduce_sum2(s, ss);

                const float mu  = s * (1.0f / (float)DCOLS);
                const float var = ss * (1.0f / (float)DCOLS) - mu * mu;
                const float rs  = rsqrtf(var + 1e-5f);

                e0[i] = (x0 - mu) * rs * g0 + b0;
                const f32x4 t1 = (x1 - mu) * rs * g1 + b1;
                *(f32x4*)(s_e1 + r * HCOL + c0) = t1;  // thread-private slot

                if (wave == 0 && i == 0) {
                    *(f32x4*)(s_q + c0) = e0[0];
                    *(f32x4*)(s_q + c1) = t1;
                    __builtin_nontemporal_store(e0[0], (f32x4*)(ob + c0));
                    __builtin_nontemporal_store(t1,    (f32x4*)(ob + c1));
                }
            }
        }

        // ---- Prefetch next batch's c0-half; stays in flight across the
        //      manual barriers (no vmcnt drain) until consumed next iter ----
        if (t + 1 < BPB) {
            const float* nb = eb + NROWS * DCOLS;
#pragma unroll
            for (int i = 0; i < RPW; ++i)
                cx0[i] = *(const f32x4*)(nb + (r0 + i) * DCOLS + c0);
        }
        __builtin_amdgcn_sched_barrier(0);

        lds_barrier();   // barrier 1: q + e1 visible

        const f32x4 q0 = *(const f32x4*)(s_q + c0);
        const f32x4 q1 = *(const f32x4*)(s_q + c1);
        const f32x4 w0 = *(const f32x4*)(s_w + c0);
        const f32x4 w1 = *(const f32x4*)(s_w + c1);

        // ---- Pass 2: scores + per-wave softmax partials (max-free:
        //      |score| <= sum|Wv_d| ~ 18, exp is safe in f32) ----
        float ex[RPW];
        float denw = 0.0f;
#pragma unroll
        for (int i = 0; i < RPW; ++i) {
            const int r = r0 + i;
            const f32x4 t1 = *(const f32x4*)(s_e1 + r * HCOL + c0);
            float p;
            p  = fast_tanh(q0.x * e0[i].x) * w0.x;
            p += fast_tanh(q0.y * e0[i].y) * w0.y;
            p += fast_tanh(q0.z * e0[i].z) * w0.z;
            p += fast_tanh(q0.w * e0[i].w) * w0.w;
            p += fast_tanh(q1.x * t1.x) * w1.x;
            p += fast_tanh(q1.y * t1.y) * w1.y;
            p += fast_tanh(q1.z * t1.z) * w1.z;
            p += fast_tanh(q1.w * t1.w) * w1.w;
            const float tot = wave_reduce_sum(p) + bias;
            const float e   = __expf(tot);
            ex[i] = (r == 0) ? 0.0f : e;   // row 0 excluded from softmax
            denw += ex[i];
        }
        if (lane == 0) s_den[wave] = denw;

        lds_barrier();   // barrier 2: partial denominators visible

        float den = 0.0f;
#pragma unroll
        for (int w = 0; w < RPW; ++w) den += s_den[w];   // broadcast reads
        const float inv = 1.0f / den;

        // ---- Pass 3: scale + store ----
#pragma unroll
        for (int i = 0; i < RPW; ++i) {
            const int r = r0 + i;
            if (r == 0) continue;   // row 0 already written (it's q)
            const float a  = ex[i] * inv;
            const f32x4 t1 = *(const f32x4*)(s_e1 + r * HCOL + c0);
            __builtin_nontemporal_store(e0[i] * a, (f32x4*)(ob + r * DCOLS + c0));
            __builtin_nontemporal_store(t1 * a,    (f32x4*)(ob + r * DCOLS + c1));
        }
    }
}

extern "C" void kernel_launch(void* const* d_in, const int* in_sizes, int n_in,
                              void* d_out, int out_size, void* d_ws, size_t ws_size,
                              hipStream_t stream) {
    const float* emb   = (const float*)d_in[0];
    const float* gamma = (const float*)d_in[1];
    const float* beta  = (const float*)d_in[2];
    const float* Wv    = (const float*)d_in[3];
    const float* bv    = (const float*)d_in[4];
    float* out = (float*)d_out;

    const int B = in_sizes[0] / (NROWS * DCOLS);
    const int grid = (B + BPB - 1) / BPB;
    fused_ln_attn_kernel<<<grid, BDIM, 0, stream>>>(emb, gamma, beta, Wv, bv, out, B);
}